// Round 25
// baseline (530.201 us; speedup 1.0000x reference)
//
#include <hip/hip_runtime.h>

constexpr int H    = 128;
constexpr int NN   = 10000;
constexpr int EE   = 160000;
constexpr int RCN  = 4;      // R*C
constexpr int NG   = 64;     // graphs per replica
constexpr int OUTF = 64;
constexpr int DSEG = 256;    // RCN*NG

using short8 = __attribute__((ext_vector_type(8))) short;
using f32x4  = __attribute__((ext_vector_type(4))) float;

// Exact-GELU via A&S 7.1.26 erf (|err|<=1.5e-7 abs) — used in GEMM epilogues
__device__ __forceinline__ float gelu_f(float x){
  float z  = x*0.70710678118654752440f;
  float az = fabsf(z);
  float t  = __builtin_amdgcn_rcpf(fmaf(az, 0.3275911f, 1.0f));
  float e  = __expf(-z*z);
  float poly = fmaf(fmaf(fmaf(fmaf(1.061405429f, t, -1.453152027f),
                              t, 1.421413741f),
                         t, -0.284496736f),
                    t, 0.254829592f) * t;
  float er = fmaf(-poly, e, 1.0f);
  er = copysignf(er, z);
  return 0.5f*x*(1.0f + er);
}

// tanh-form GELU (|dev from exact| ~3e-4) — k_agg hot loop only
__device__ __forceinline__ float gelu_t(float x){
  float u = fmaf(0.044715f*x, x*x, x) * 1.5957691216057308f;
  float e = __expf(u);
  float th = 1.0f - 2.0f*__builtin_amdgcn_rcpf(e + 1.0f);
  return 0.5f*x*(1.0f + th);
}

// RNE 2-way split
__device__ __forceinline__ void split2(float x, unsigned short& h, unsigned short& m){
  unsigned int u = __float_as_uint(x);
  unsigned int rh = u + 0x7FFF + ((u>>16)&1);
  h = (unsigned short)(rh>>16);
  float fh = __uint_as_float((unsigned int)h << 16);
  float r1 = x - fh;
  unsigned int u1 = __float_as_uint(r1);
  unsigned int rm = u1 + 0x7FFF + ((u1>>16)&1);
  m = (unsigned short)(rm>>16);
}

__device__ __forceinline__ unsigned short bf16rne(float x){
  unsigned int u = __float_as_uint(x);
  return (unsigned short)((u + 0x7FFF + ((u>>16)&1))>>16);
}
__device__ __forceinline__ float bf2f(unsigned short v){
  return __uint_as_float((unsigned int)v << 16);
}

// ---------- CSR build
__global__ void k_hist(const int* __restrict__ dst, int* __restrict__ cnt){
  int e = blockIdx.x*256 + threadIdx.x;
  if(e < EE) atomicAdd(&cnt[dst[e]], 1);
}

// scan + degree histogram fused
__global__ __launch_bounds__(1024) void k_scan(const int* __restrict__ cnt,
                                               int* __restrict__ rs, int* __restrict__ cur,
                                               int* __restrict__ dcnt){
  __shared__ int part[1024];
  int t = threadIdx.x;
  const int CH = 10;
  int base = t*CH;
  int s = 0;
  #pragma unroll
  for(int j=0;j<CH;j++){ int i = base+j; if(i<NN) s += cnt[i]; }
  part[t] = s;
  __syncthreads();
  for(int off=1; off<1024; off<<=1){
    int v = (t>=off) ? part[t-off] : 0;
    __syncthreads();
    part[t] += v;
    __syncthreads();
  }
  int run = (t==0) ? 0 : part[t-1];
  #pragma unroll
  for(int j=0;j<CH;j++){
    int i = base+j;
    if(i<NN){
      int d = cnt[i];
      rs[i] = run; cur[i] = run; run += d;
      if(d > 255) d = 255;
      atomicAdd(&dcnt[d], 1);
    }
  }
  if(t == 1023) rs[NN] = part[1023];
}

__global__ void k_fill(const int* __restrict__ dst,
                       int* __restrict__ cur, int* __restrict__ eid){
  int e = blockIdx.x*256 + threadIdx.x;
  if(e >= EE) return;
  int p = atomicAdd(&cur[dst[e]], 1);
  eid[p] = e;
}

// ---------- wave-parallel bitonic sort
__global__ __launch_bounds__(256) void k_sortcsr(const int* __restrict__ rs, int* __restrict__ eid,
                          const int* __restrict__ src, int* __restrict__ esrc){
  int wid  = (blockIdx.x*256 + threadIdx.x) >> 6;
  int lane = threadIdx.x & 63;
  if(wid >= NN) return;
  int jb = rs[wid], je = rs[wid+1];
  int deg = je - jb;
  if(deg <= 0) return;
  if(deg == 1){
    if(lane == 0) esrc[jb] = src[eid[jb]];
    return;
  }
  if(deg <= 64){
    int v = (lane < deg) ? eid[jb + lane] : 0x7FFFFFFF;
    #pragma unroll
    for(int k=2; k<=64; k<<=1){
      #pragma unroll
      for(int j=k>>1; j>0; j>>=1){
        int o = __shfl_xor(v, j, 64);
        bool desc  = (lane & k) != 0;
        bool lower = (lane & j) == 0;
        v = ((lower != desc) ? min(v,o) : max(v,o));
      }
    }
    if(lane < deg){
      eid[jb+lane]  = v;
      esrc[jb+lane] = src[v];
    }
  } else if(lane == 0){
    for(int j=jb+1; j<je; j++){
      int v = eid[j];
      int k = j-1;
      while(k >= jb && eid[k] > v){ eid[k+1] = eid[k]; k--; }
      eid[k+1] = v;
    }
    for(int j=jb; j<je; j++) esrc[j] = src[eid[j]];
  }
}

// ---------- fused small kernels: block 0 = desc-degree scan, block 1 = gbounds
__global__ __launch_bounds__(256) void k_misc(const int* __restrict__ dcnt,
                                              int* __restrict__ dcur,
                                              const int* __restrict__ batch,
                                              int* __restrict__ gs){
  int t = threadIdx.x;
  if(blockIdx.x == 0){
    __shared__ int buf[256];
    int orig = dcnt[255-t];
    buf[t] = orig;
    __syncthreads();
    for(int off=1; off<256; off<<=1){
      int v = (t>=off) ? buf[t-off] : 0;
      __syncthreads();
      buf[t] += v;
      __syncthreads();
    }
    dcur[255-t] = buf[t] - orig;
  } else {
    if(t > NG) return;
    if(t == NG){ gs[NG] = NN; return; }
    int lo = 0, hi = NN;
    while(lo < hi){
      int mid = (lo+hi)>>1;
      if(batch[mid] < t) lo = mid+1; else hi = mid;
    }
    gs[t] = lo;
  }
}

__global__ void k_dfill(const int* __restrict__ rs, int* __restrict__ dcur,
                        int* __restrict__ nord){
  int n = blockIdx.x*256 + threadIdx.x;
  if(n >= NN) return;
  int deg = rs[n+1] - rs[n];
  if(deg > 255) deg = 255;
  int p = atomicAdd(&dcur[deg], 1);
  nord[p] = n;
}

// ---------- single segmented weight-split kernel
__device__ __forceinline__ void splitW_one(const float* W, unsigned short* oh,
                                           unsigned short* om, int tid, int N){
  int k = tid / N;
  int n = tid - k*N;
  int mat = k >> 7; k &= 127;
  int NF = N >> 4;
  int ks = k >> 5, kk = k & 31;
  int nf = n >> 4;
  int lane = (n & 15) + 16*((kk & 15) >> 2);
  int e = 4*(kk >> 4) + (kk & 3);
  size_t idx = (size_t)mat*128*N + ((size_t)(ks*NF + nf)*64 + lane)*8 + e;
  unsigned short hh, mm;
  split2(W[tid], hh, mm);
  oh[idx] = hh; om[idx] = mm;
}

__global__ void k_splitWall(const float* __restrict__ bond_W,
                            const float* __restrict__ conv_W1,
                            const float* __restrict__ conv_W2,
                            const float* __restrict__ mlp_W1,
                            const float* __restrict__ mlp_W2,
                            unsigned short* WBh,  unsigned short* WBm,
                            unsigned short* WC1h, unsigned short* WC1m,
                            unsigned short* WC2h, unsigned short* WC2m,
                            unsigned short* WM1h, unsigned short* WM1m,
                            unsigned short* WM2h, unsigned short* WM2m){
  int gid = blockIdx.x*256 + threadIdx.x;
  const int S0 = 3*128*128;
  const int S1 = S0 + 3*128*128;
  const int S2 = S1 + 3*128*128;
  const int S3 = S2 + 128*128;
  const int S4 = S3 + 128*64;
  if(gid < S0)      splitW_one(bond_W,  WBh,  WBm,  gid,      128);
  else if(gid < S1) splitW_one(conv_W1, WC1h, WC1m, gid-S0,   128);
  else if(gid < S2) splitW_one(conv_W2, WC2h, WC2m, gid-S1,   128);
  else if(gid < S3) splitW_one(mlp_W1,  WM1h, WM1m, gid-S2,   128);
  else if(gid < S4) splitW_one(mlp_W2,  WM2h, WM2m, gid-S3,    64);
}

// ---------- edge prep: CSR-permuted edge_attr bf16 plane + edge mask (fused)
__global__ void k_edgeprep(const float* __restrict__ A, const int* __restrict__ eid,
                           const int* __restrict__ src, const int* __restrict__ dst,
                           const float* __restrict__ nm,
                           unsigned short* __restrict__ oh, float4* __restrict__ em4p){
  int tid = blockIdx.x*256 + threadIdx.x;
  if(tid >= EE*32) return;
  int j = tid >> 5, kq = tid & 31;
  int k = kq*4;
  int e = eid[j];
  float4 v = *(const float4*)&A[(size_t)e*H + k];
  ushort4 hh;
  hh.x = bf16rne(v.x); hh.y = bf16rne(v.y);
  hh.z = bf16rne(v.z); hh.w = bf16rne(v.w);
  *(ushort4*)&oh[(size_t)j*H + k] = hh;
  if(kq == 0){
    int s = src[e], d = dst[e];
    float4 m;
    m.x = nm[0*NN+s]*nm[0*NN+d];
    m.y = nm[1*NN+s]*nm[1*NN+d];
    m.z = nm[2*NN+s]*nm[2*NN+d];
    m.w = nm[3*NN+s]*nm[3*NN+d];
    em4p[j] = m;
  }
}

// ---------- 3-layer emb GEMM, single A pass, 4-deep W prefetch ring
__global__ __launch_bounds__(256) void k_egemm(
    const unsigned short* __restrict__ Ah,
    const unsigned short* __restrict__ WBh, const unsigned short* __restrict__ WBm,
    const float* __restrict__ bond_b, unsigned short* __restrict__ embB3){
  int t = threadIdx.x;
  int w = t >> 6, lane = t & 63;
  int m15 = lane & 15, kg = lane >> 4;
  int rowbase = blockIdx.x*128;

  short8 ahf[2][4];
  #pragma unroll
  for(int mf=0;mf<2;mf++){
    int arow = rowbase + w*32 + mf*16 + m15;
    #pragma unroll
    for(int ks=0;ks<4;ks++){
      size_t base = (size_t)arow*H + ks*32 + kg*4;
      ushort4 hlo = *(const ushort4*)&Ah[base];
      ushort4 hhi = *(const ushort4*)&Ah[base + 16];
      ahf[mf][ks] = (short8){(short)hlo.x,(short)hlo.y,(short)hlo.z,(short)hlo.w,
                             (short)hhi.x,(short)hhi.y,(short)hhi.z,(short)hhi.w};
    }
  }

  for(int layer=0; layer<3; layer++){
    const unsigned short* Wh = WBh + layer*16384;
    const unsigned short* Wm = WBm + layer*16384;
    const float* bias = bond_b + layer*H;
    unsigned short* Oh = embB3 + (size_t)layer*EE*H;

    const int SMAX = 31;
    auto ldW = [&](int s, short8* d){
      size_t widx = ((size_t)s*64 + lane)*8;
      d[0] = *(const short8*)&Wh[widx];
      d[1] = *(const short8*)&Wm[widx];
    };

    f32x4 acc[2][8];
    #pragma unroll
    for(int mf=0;mf<2;mf++)
      #pragma unroll
      for(int nf=0;nf<8;nf++) acc[mf][nf] = (f32x4){0.f,0.f,0.f,0.f};

    short8 wb[4][2];
    ldW(0, wb[0]); ldW(1, wb[1]); ldW(2, wb[2]); ldW(3, wb[3]);

    for(int ks=0;ks<4;ks++){
      #pragma unroll
      for(int nf=0;nf<8;nf++){
        int s = ks*8 + nf;
        const int slot = nf & 3;
        #pragma unroll
        for(int mf=0;mf<2;mf++){
          acc[mf][nf] = __builtin_amdgcn_mfma_f32_16x16x32_bf16(ahf[mf][ks], wb[slot][0], acc[mf][nf], 0,0,0);
          acc[mf][nf] = __builtin_amdgcn_mfma_f32_16x16x32_bf16(ahf[mf][ks], wb[slot][1], acc[mf][nf], 0,0,0);
        }
        int ns = s + 4; if(ns > SMAX) ns = SMAX;
        ldW(ns, wb[slot]);
      }
    }
    #pragma unroll
    for(int mf=0;mf<2;mf++){
      #pragma unroll
      for(int nf=0;nf<8;nf++){
        int gcol = nf*16 + m15;
        float bv = bias[gcol];
        #pragma unroll
        for(int r=0;r<4;r++){
          int grow = rowbase + w*32 + mf*16 + kg*4 + r;
          Oh[(size_t)grow*H + gcol] = bf16rne(acc[mf][nf][r] + bv);
        }
      }
    }
  }
}

// ---------- FUSED double GEMM, 16 rows/wave, wave-private u tile, 4-deep W ring
template<int NFO2, bool G2, int OMODE>
__global__ __launch_bounds__(256) void k_fuse2(
    const unsigned short* __restrict__ Ah, const unsigned short* __restrict__ Am,
    const unsigned short* __restrict__ W1h, const unsigned short* __restrict__ W1m,
    const float* __restrict__ b1,
    const unsigned short* __restrict__ W2h, const unsigned short* __restrict__ W2m,
    const float* __restrict__ b2,
    float* __restrict__ Cf,
    unsigned short* __restrict__ Oh, unsigned short* __restrict__ Om, int nrows){
  __shared__ unsigned int Ul[4*16*132];
  int t = threadIdx.x;
  int w = t >> 6, lane = t & 63;
  int m15 = lane & 15, kg = lane >> 4;
  int rowbase = blockIdx.x*64;
  unsigned int* Uw = &Ul[w*16*132];

  int r0 = rowbase + w*16 + m15;
  int arow = (r0 < nrows) ? r0 : (nrows-1);

  // ---- phase 1: u = gelu(A@W1 + b1)
  {
    const int SMAX = 31;
    auto ldW = [&](int s, short8* d){
      size_t widx = ((size_t)s*64 + lane)*8;
      d[0] = *(const short8*)&W1h[widx];
      d[1] = *(const short8*)&W1m[widx];
    };
    f32x4 acc[8];
    #pragma unroll
    for(int nf=0;nf<8;nf++) acc[nf] = (f32x4){0.f,0.f,0.f,0.f};
    short8 wb[4][2];
    ldW(0, wb[0]); ldW(1, wb[1]); ldW(2, wb[2]); ldW(3, wb[3]);
    for(int ks=0;ks<4;ks++){
      short8 ah, am;
      {
        size_t base = (size_t)arow*H + ks*32 + kg*4;
        ushort4 hlo = *(const ushort4*)&Ah[base];
        ushort4 hhi = *(const ushort4*)&Ah[base + 16];
        ushort4 mlo = *(const ushort4*)&Am[base];
        ushort4 mhi = *(const ushort4*)&Am[base + 16];
        ah = (short8){(short)hlo.x,(short)hlo.y,(short)hlo.z,(short)hlo.w,
                      (short)hhi.x,(short)hhi.y,(short)hhi.z,(short)hhi.w};
        am = (short8){(short)mlo.x,(short)mlo.y,(short)mlo.z,(short)mlo.w,
                      (short)mhi.x,(short)mhi.y,(short)mhi.z,(short)mhi.w};
      }
      #pragma unroll
      for(int nf=0;nf<8;nf++){
        int s = ks*8 + nf;
        const int slot = nf & 3;
        acc[nf] = __builtin_amdgcn_mfma_f32_16x16x32_bf16(ah, wb[slot][0], acc[nf], 0,0,0);
        acc[nf] = __builtin_amdgcn_mfma_f32_16x16x32_bf16(ah, wb[slot][1], acc[nf], 0,0,0);
        acc[nf] = __builtin_amdgcn_mfma_f32_16x16x32_bf16(am, wb[slot][0], acc[nf], 0,0,0);
        int ns = s + 4; if(ns > SMAX) ns = SMAX;
        ldW(ns, wb[slot]);
      }
    }
    #pragma unroll
    for(int nf=0;nf<8;nf++){
      float bv = b1[nf*16 + m15];
      #pragma unroll
      for(int r=0;r<4;r++){
        float v = gelu_f(acc[nf][r] + bv);
        unsigned short hh, mm2;
        split2(v, hh, mm2);
        int wrow = kg*4 + r;
        Uw[wrow*132 + nf*16 + m15] = (unsigned)hh | ((unsigned)mm2 << 16);
      }
    }
  }
  // no barrier: u tile is strictly wave-private

  // ---- phase 2: out = act2(u @ W2 + b2)
  {
    const int SMAX = 4*NFO2 - 1;
    auto ldW = [&](int s, short8* d){
      size_t widx = ((size_t)s*64 + lane)*8;
      d[0] = *(const short8*)&W2h[widx];
      d[1] = *(const short8*)&W2m[widx];
    };
    f32x4 acc[NFO2];
    #pragma unroll
    for(int nf=0;nf<NFO2;nf++) acc[nf] = (f32x4){0.f,0.f,0.f,0.f};
    short8 wb[4][2];
    ldW(0, wb[0]);
    ldW(1 <= SMAX ? 1 : SMAX, wb[1]);
    ldW(2 <= SMAX ? 2 : SMAX, wb[2]);
    ldW(3 <= SMAX ? 3 : SMAX, wb[3]);
    for(int ks=0;ks<4;ks++){
      short8 ah, am;
      {
        const unsigned int* base = &Uw[m15*132 + ks*32 + kg*4];
        uint4 q0 = *(const uint4*)base;
        uint4 q1 = *(const uint4*)(base + 16);
        unsigned h0 = (q0.x & 0xFFFFu) | (q0.y << 16);
        unsigned h1 = (q0.z & 0xFFFFu) | (q0.w << 16);
        unsigned h2 = (q1.x & 0xFFFFu) | (q1.y << 16);
        unsigned h3 = (q1.z & 0xFFFFu) | (q1.w << 16);
        unsigned M0 = (q0.x >> 16) | (q0.y & 0xFFFF0000u);
        unsigned M1 = (q0.z >> 16) | (q0.w & 0xFFFF0000u);
        unsigned M2 = (q1.x >> 16) | (q1.y & 0xFFFF0000u);
        unsigned M3 = (q1.z >> 16) | (q1.w & 0xFFFF0000u);
        union { uint4 u; short8 s; } cvh, cvm;
        cvh.u = (uint4){h0,h1,h2,h3};
        cvm.u = (uint4){M0,M1,M2,M3};
        ah = cvh.s; am = cvm.s;
      }
      #pragma unroll
      for(int nf=0;nf<NFO2;nf++){
        int s = ks*NFO2 + nf;
        const int slot = nf & 3;
        acc[nf] = __builtin_amdgcn_mfma_f32_16x16x32_bf16(ah, wb[slot][0], acc[nf], 0,0,0);
        acc[nf] = __builtin_amdgcn_mfma_f32_16x16x32_bf16(ah, wb[slot][1], acc[nf], 0,0,0);
        acc[nf] = __builtin_amdgcn_mfma_f32_16x16x32_bf16(am, wb[slot][0], acc[nf], 0,0,0);
        int ns = s + 4; if(ns > SMAX) ns = SMAX;
        ldW(ns, wb[slot]);
      }
    }
    #pragma unroll
    for(int nf=0;nf<NFO2;nf++){
      int gcol = nf*16 + m15;
      float bv = b2[gcol];
      #pragma unroll
      for(int r=0;r<4;r++){
        int grow = rowbase + w*16 + kg*4 + r;
        if(grow >= nrows) continue;
        float v = acc[nf][r] + bv;
        if(G2) v = gelu_f(v);
        size_t idx = (size_t)grow*(NFO2*16) + gcol;
        if(OMODE == 0) Cf[idx] = v;
        if(OMODE == 1){
          unsigned short hh, mm2;
          split2(v, hh, mm2);
          Oh[idx] = hh; Om[idx] = mm2;
        }
        if(OMODE == 2) Oh[idx] = bf16rne(v);
      }
    }
  }
}

// ---------- aggregation: TWO WAVES PER NODE (rc-pair per wave), CSR streams,
// bf16 emb, fp32 node-major h gather, 3-slot shifting pipeline, degree-desc order
template<bool FIRST>
__global__ __launch_bounds__(256) void k_agg(const float* __restrict__ hin,
                       const unsigned short* __restrict__ embB, const float4* __restrict__ em4p,
                       const int* __restrict__ rs, const int* __restrict__ esrc,
                       const int* __restrict__ nord,
                       const float* __restrict__ epsp,
                       unsigned short* __restrict__ Th, unsigned short* __restrict__ Tm){
  int t = threadIdx.x;
  int w = t >> 6;
  int lane = t & 63;
  int half = lane >> 5;
  int l32 = lane & 31;
  int wid = blockIdx.x*4 + w;
  int n = nord[wid >> 1];
  int pair = wid & 1;           // wave-uniform
  int rc = pair*2 + half;       // this lane's replica
  int d0 = l32*4;
  float4 acc = {0.f,0.f,0.f,0.f};
  int jb = rs[n], je = rs[n+1];

  float4 evs[3], hs[3];
  float  ms[3];

  auto ld = [&](int j, int slot){
    int s = esrc[j];
    ushort4 e4 = *(const ushort4*)&embB[(size_t)j*H + d0];
    evs[slot].x = bf2f(e4.x); evs[slot].y = bf2f(e4.y);
    evs[slot].z = bf2f(e4.z); evs[slot].w = bf2f(e4.w);
    float4 m = em4p[j];
    float mlo = pair ? m.z : m.x;
    float mhi = pair ? m.w : m.y;
    ms[slot] = half ? mhi : mlo;
    if(FIRST){
      hs[slot] = *(const float4*)&hin[(size_t)s*H + d0];
    } else {
      hs[slot] = *(const float4*)&hin[((size_t)s*RCN + rc)*H + d0];
    }
  };

  if(jb < je){
    ld(jb, 0);
    if(jb+1 < je) ld(jb+1, 1);
    if(jb+2 < je) ld(jb+2, 2);
    for(int j=jb; j<je; j++){
      float4 ev0 = evs[0], h0 = hs[0];
      float  m0 = ms[0];
      evs[0]=evs[1]; hs[0]=hs[1]; ms[0]=ms[1];
      evs[1]=evs[2]; hs[1]=hs[2]; ms[1]=ms[2];
      if(j+3 < je) ld(j+3, 2);
      acc.x += gelu_t(h0.x+ev0.x)*m0;
      acc.y += gelu_t(h0.y+ev0.y)*m0;
      acc.z += gelu_t(h0.z+ev0.z)*m0;
      acc.w += gelu_t(h0.w+ev0.w)*m0;
    }
  }
  float e1 = 1.0f + epsp[0];
  {
    const float* hb = FIRST ? (hin + (size_t)n*H) : (hin + ((size_t)n*RCN + rc)*H);
    float4 hv = *(const float4*)&hb[d0];
    float4 o;
    o.x = e1*hv.x + acc.x; o.y = e1*hv.y + acc.y;
    o.z = e1*hv.z + acc.z; o.w = e1*hv.w + acc.w;
    int row = n*RCN + rc;               // node-major
    ushort4 hh, mm;
    split2(o.x, hh.x, mm.x);
    split2(o.y, hh.y, mm.y);
    split2(o.z, hh.z, mm.z);
    split2(o.w, hh.w, mm.w);
    size_t idx = (size_t)row*H + d0;
    *(ushort4*)&Th[idx] = hh;
    *(ushort4*)&Tm[idx] = mm;
  }
}

// ---------- deterministic masked segment mean (node-major y rows)
__global__ __launch_bounds__(64) void k_pool(const float* __restrict__ y, const float* __restrict__ nm,
                       const int* __restrict__ gs, float* __restrict__ out){
  int seg = blockIdx.x;
  int rc = seg / NG;
  int g  = seg - rc*NG;
  int c  = threadIdx.x;
  int nb = gs[g], ne = gs[g+1];
  float num = 0.f, den = 0.f;
  for(int n=nb; n<ne; n++){
    float w = nm[rc*NN + n];
    num += y[((size_t)n*RCN + rc)*OUTF + c] * w;
    den += w;
  }
  out[seg*OUTF + c] = num / fmaxf(den, 1e-12f);
}

extern "C" void kernel_launch(void* const* d_in, const int* in_sizes, int n_in,
                              void* d_out, int out_size, void* d_ws, size_t ws_size,
                              hipStream_t stream){
  const float* x         = (const float*)d_in[0];
  const float* edge_attr = (const float*)d_in[1];
  const float* node_mask = (const float*)d_in[2];
  const float* bond_W    = (const float*)d_in[3];
  const float* bond_b    = (const float*)d_in[4];
  const float* epsv      = (const float*)d_in[5];
  const float* conv_W1   = (const float*)d_in[6];
  const float* conv_b1   = (const float*)d_in[7];
  const float* conv_W2   = (const float*)d_in[8];
  const float* conv_b2   = (const float*)d_in[9];
  const float* mlp_W1    = (const float*)d_in[10];
  const float* mlp_b1    = (const float*)d_in[11];
  const float* mlp_W2    = (const float*)d_in[12];
  const float* mlp_b2    = (const float*)d_in[13];
  const int*   eidx      = (const int*)d_in[14];
  const int*   batch     = (const int*)d_in[15];
  const int* srcp = eidx;
  const int* dstp = eidx + EE;

  char* p = (char*)d_ws;
  auto alloc = [&](size_t bytes)->char*{
    char* r = p; p += (bytes + 255) & ~size_t(255); return r;
  };
  float*  h    = (float*) alloc((size_t)RCN*NN*H*4);      // 20.5 MB fp32 node-major
  unsigned short* embB3 = (unsigned short*)alloc((size_t)3*EE*H*2); // 123 MB bf16 (3 layers)
  float4* em4p = (float4*)alloc((size_t)EE*16);           //  2.6 MB
  float*  y    = (float*) alloc((size_t)RCN*NN*OUTF*4);   // 10.2 MB
  int*    cnt  = (int*)   alloc((size_t)NN*4);
  int*    rs   = (int*)   alloc((size_t)(NN+1)*4);
  int*    cur  = (int*)   alloc((size_t)NN*4);
  int*    eid  = (int*)   alloc((size_t)EE*4);
  int*    esrc = (int*)   alloc((size_t)EE*4);
  int*    gs   = (int*)   alloc((size_t)(NG+1)*4);
  int*    dcnt = (int*)   alloc((size_t)256*4);
  int*    dcur = (int*)   alloc((size_t)256*4);
  int*    nord = (int*)   alloc((size_t)NN*4);
  // weight planes (bf16x2, frag-linear)
  unsigned short* WBh  = (unsigned short*)alloc((size_t)3*16384*2);
  unsigned short* WBm  = (unsigned short*)alloc((size_t)3*16384*2);
  unsigned short* WC1h = (unsigned short*)alloc((size_t)3*16384*2);
  unsigned short* WC1m = (unsigned short*)alloc((size_t)3*16384*2);
  unsigned short* WC2h = (unsigned short*)alloc((size_t)3*16384*2);
  unsigned short* WC2m = (unsigned short*)alloc((size_t)3*16384*2);
  unsigned short* WM1h = (unsigned short*)alloc((size_t)16384*2);
  unsigned short* WM1m = (unsigned short*)alloc((size_t)16384*2);
  unsigned short* WM2h = (unsigned short*)alloc((size_t)8192*2);
  unsigned short* WM2m = (unsigned short*)alloc((size_t)8192*2);
  // edge_attr single bf16 plane (CSR-permuted, row-major): 41 MB
  unsigned short* EAh  = (unsigned short*)alloc((size_t)EE*H*2);
  // node activation planes (row-major bf16x2)
  const size_t NPB = (size_t)RCN*NN*H*2;
  unsigned short* TBh = (unsigned short*)alloc(NPB);
  unsigned short* TBm = (unsigned short*)alloc(NPB);
  if((size_t)(p - (char*)d_ws) > ws_size) return;   // total ~222 MB

  hipMemsetAsync(cnt, 0, (size_t)NN*4, stream);
  hipMemsetAsync(dcnt, 0, (size_t)256*4, stream);

  k_hist     <<<(EE+255)/256, 256, 0, stream>>>(dstp, cnt);
  k_scan     <<<1, 1024, 0, stream>>>(cnt, rs, cur, dcnt);
  k_fill     <<<(EE+255)/256, 256, 0, stream>>>(dstp, cur, eid);
  k_sortcsr  <<<(NN*64+255)/256, 256, 0, stream>>>(rs, eid, srcp, esrc);
  k_misc     <<<2, 256, 0, stream>>>(dcnt, dcur, batch, gs);
  k_dfill    <<<(NN+255)/256, 256, 0, stream>>>(rs, dcur, nord);
  k_edgeprep <<<(EE*32+255)/256, 256, 0, stream>>>(edge_attr, eid, srcp, dstp,
                                                   node_mask, EAh, em4p);
  k_splitWall<<<(172032+255)/256, 256, 0, stream>>>(bond_W, conv_W1, conv_W2, mlp_W1, mlp_W2,
                                                    WBh, WBm, WC1h, WC1m, WC2h, WC2m,
                                                    WM1h, WM1m, WM2h, WM2m);
  // all 3 emb layers in one launch, single A pass
  k_egemm    <<<EE/128, 256, 0, stream>>>(EAh, WBh, WBm, bond_b, embB3);

  const int NROWS = RCN*NN;
  const int GB_F = (NROWS+63)/64;      // 625 blocks for fuse2
  const int GB_A = NN*2/4;             // 5000 blocks: 2 waves per node
  for(int l=0; l<3; l++){
    size_t wo = (size_t)l*16384;
    const unsigned short* embB = embB3 + (size_t)l*EE*H;
    if(l == 0)
      k_agg<true ><<<GB_A, 256, 0, stream>>>(x, embB, em4p, rs, esrc, nord,
                                             epsv + l, TBh, TBm);
    else
      k_agg<false><<<GB_A, 256, 0, stream>>>(h, embB, em4p, rs, esrc, nord,
                                             epsv + l, TBh, TBm);
    // fused conv: h = gelu(gelu(t@W1+b1)@W2+b2)
    if(l < 2)
      k_fuse2<8,true,0><<<GB_F, 256, 0, stream>>>(
          TBh, TBm, WC1h+wo, WC1m+wo, conv_b1 + l*H,
          WC2h+wo, WC2m+wo, conv_b2 + l*H, h, nullptr, nullptr, NROWS);
    else
      k_fuse2<8,true,1><<<GB_F, 256, 0, stream>>>(
          TBh, TBm, WC1h+wo, WC1m+wo, conv_b1 + l*H,
          WC2h+wo, WC2m+wo, conv_b2 + l*H, nullptr, TBh, TBm, NROWS);
  }
  // fused MLP: y = gelu(hp@W1+b1)@W2+b2
  k_fuse2<4,false,0><<<GB_F, 256, 0, stream>>>(
      TBh, TBm, WM1h, WM1m, mlp_b1, WM2h, WM2m, mlp_b2,
      y, nullptr, nullptr, NROWS);
  k_pool<<<DSEG, 64, 0, stream>>>(y, node_mask, gs, (float*)d_out);
}

// Round 26
// 514.805 us; speedup vs baseline: 1.0299x; 1.0299x over previous
//
#include <hip/hip_runtime.h>

constexpr int H    = 128;
constexpr int NN   = 10000;
constexpr int EE   = 160000;
constexpr int RCN  = 4;      // R*C
constexpr int NG   = 64;     // graphs per replica
constexpr int OUTF = 64;
constexpr int DSEG = 256;    // RCN*NG

using short8 = __attribute__((ext_vector_type(8))) short;
using f32x4  = __attribute__((ext_vector_type(4))) float;

// Exact-GELU via A&S 7.1.26 erf (|err|<=1.5e-7 abs) — used in GEMM epilogues
__device__ __forceinline__ float gelu_f(float x){
  float z  = x*0.70710678118654752440f;
  float az = fabsf(z);
  float t  = __builtin_amdgcn_rcpf(fmaf(az, 0.3275911f, 1.0f));
  float e  = __expf(-z*z);
  float poly = fmaf(fmaf(fmaf(fmaf(1.061405429f, t, -1.453152027f),
                              t, 1.421413741f),
                         t, -0.284496736f),
                    t, 0.254829592f) * t;
  float er = fmaf(-poly, e, 1.0f);
  er = copysignf(er, z);
  return 0.5f*x*(1.0f + er);
}

// tanh-form GELU (|dev from exact| ~3e-4) — k_agg hot loop only
__device__ __forceinline__ float gelu_t(float x){
  float u = fmaf(0.044715f*x, x*x, x) * 1.5957691216057308f;
  float e = __expf(u);
  float th = 1.0f - 2.0f*__builtin_amdgcn_rcpf(e + 1.0f);
  return 0.5f*x*(1.0f + th);
}

// RNE 2-way split
__device__ __forceinline__ void split2(float x, unsigned short& h, unsigned short& m){
  unsigned int u = __float_as_uint(x);
  unsigned int rh = u + 0x7FFF + ((u>>16)&1);
  h = (unsigned short)(rh>>16);
  float fh = __uint_as_float((unsigned int)h << 16);
  float r1 = x - fh;
  unsigned int u1 = __float_as_uint(r1);
  unsigned int rm = u1 + 0x7FFF + ((u1>>16)&1);
  m = (unsigned short)(rm>>16);
}

__device__ __forceinline__ unsigned short bf16rne(float x){
  unsigned int u = __float_as_uint(x);
  return (unsigned short)((u + 0x7FFF + ((u>>16)&1))>>16);
}
__device__ __forceinline__ float bf2f(unsigned short v){
  return __uint_as_float((unsigned int)v << 16);
}

// ---------- CSR build
__global__ void k_hist(const int* __restrict__ dst, int* __restrict__ cnt){
  int e = blockIdx.x*256 + threadIdx.x;
  if(e < EE) atomicAdd(&cnt[dst[e]], 1);
}

// scan + degree histogram fused
__global__ __launch_bounds__(1024) void k_scan(const int* __restrict__ cnt,
                                               int* __restrict__ rs, int* __restrict__ cur,
                                               int* __restrict__ dcnt){
  __shared__ int part[1024];
  int t = threadIdx.x;
  const int CH = 10;
  int base = t*CH;
  int s = 0;
  #pragma unroll
  for(int j=0;j<CH;j++){ int i = base+j; if(i<NN) s += cnt[i]; }
  part[t] = s;
  __syncthreads();
  for(int off=1; off<1024; off<<=1){
    int v = (t>=off) ? part[t-off] : 0;
    __syncthreads();
    part[t] += v;
    __syncthreads();
  }
  int run = (t==0) ? 0 : part[t-1];
  #pragma unroll
  for(int j=0;j<CH;j++){
    int i = base+j;
    if(i<NN){
      int d = cnt[i];
      rs[i] = run; cur[i] = run; run += d;
      if(d > 255) d = 255;
      atomicAdd(&dcnt[d], 1);
    }
  }
  if(t == 1023) rs[NN] = part[1023];
}

__global__ void k_fill(const int* __restrict__ dst,
                       int* __restrict__ cur, int* __restrict__ eid){
  int e = blockIdx.x*256 + threadIdx.x;
  if(e >= EE) return;
  int p = atomicAdd(&cur[dst[e]], 1);
  eid[p] = e;
}

// ---------- wave-parallel bitonic sort
__global__ __launch_bounds__(256) void k_sortcsr(const int* __restrict__ rs, int* __restrict__ eid,
                          const int* __restrict__ src, int* __restrict__ esrc){
  int wid  = (blockIdx.x*256 + threadIdx.x) >> 6;
  int lane = threadIdx.x & 63;
  if(wid >= NN) return;
  int jb = rs[wid], je = rs[wid+1];
  int deg = je - jb;
  if(deg <= 0) return;
  if(deg == 1){
    if(lane == 0) esrc[jb] = src[eid[jb]];
    return;
  }
  if(deg <= 64){
    int v = (lane < deg) ? eid[jb + lane] : 0x7FFFFFFF;
    #pragma unroll
    for(int k=2; k<=64; k<<=1){
      #pragma unroll
      for(int j=k>>1; j>0; j>>=1){
        int o = __shfl_xor(v, j, 64);
        bool desc  = (lane & k) != 0;
        bool lower = (lane & j) == 0;
        v = ((lower != desc) ? min(v,o) : max(v,o));
      }
    }
    if(lane < deg){
      eid[jb+lane]  = v;
      esrc[jb+lane] = src[v];
    }
  } else if(lane == 0){
    for(int j=jb+1; j<je; j++){
      int v = eid[j];
      int k = j-1;
      while(k >= jb && eid[k] > v){ eid[k+1] = eid[k]; k--; }
      eid[k+1] = v;
    }
    for(int j=jb; j<je; j++) esrc[j] = src[eid[j]];
  }
}

// ---------- fused small kernels: block 0 = desc-degree scan, block 1 = gbounds
__global__ __launch_bounds__(256) void k_misc(const int* __restrict__ dcnt,
                                              int* __restrict__ dcur,
                                              const int* __restrict__ batch,
                                              int* __restrict__ gs){
  int t = threadIdx.x;
  if(blockIdx.x == 0){
    __shared__ int buf[256];
    int orig = dcnt[255-t];
    buf[t] = orig;
    __syncthreads();
    for(int off=1; off<256; off<<=1){
      int v = (t>=off) ? buf[t-off] : 0;
      __syncthreads();
      buf[t] += v;
      __syncthreads();
    }
    dcur[255-t] = buf[t] - orig;
  } else {
    if(t > NG) return;
    if(t == NG){ gs[NG] = NN; return; }
    int lo = 0, hi = NN;
    while(lo < hi){
      int mid = (lo+hi)>>1;
      if(batch[mid] < t) lo = mid+1; else hi = mid;
    }
    gs[t] = lo;
  }
}

__global__ void k_dfill(const int* __restrict__ rs, int* __restrict__ dcur,
                        int* __restrict__ nord){
  int n = blockIdx.x*256 + threadIdx.x;
  if(n >= NN) return;
  int deg = rs[n+1] - rs[n];
  if(deg > 255) deg = 255;
  int p = atomicAdd(&dcur[deg], 1);
  nord[p] = n;
}

// ---------- single segmented weight-split kernel
__device__ __forceinline__ void splitW_one(const float* W, unsigned short* oh,
                                           unsigned short* om, int tid, int N){
  int k = tid / N;
  int n = tid - k*N;
  int mat = k >> 7; k &= 127;
  int NF = N >> 4;
  int ks = k >> 5, kk = k & 31;
  int nf = n >> 4;
  int lane = (n & 15) + 16*((kk & 15) >> 2);
  int e = 4*(kk >> 4) + (kk & 3);
  size_t idx = (size_t)mat*128*N + ((size_t)(ks*NF + nf)*64 + lane)*8 + e;
  unsigned short hh, mm;
  split2(W[tid], hh, mm);
  oh[idx] = hh; om[idx] = mm;
}

__global__ void k_splitWall(const float* __restrict__ bond_W,
                            const float* __restrict__ conv_W1,
                            const float* __restrict__ conv_W2,
                            const float* __restrict__ mlp_W1,
                            const float* __restrict__ mlp_W2,
                            unsigned short* WBh,  unsigned short* WBm,
                            unsigned short* WC1h, unsigned short* WC1m,
                            unsigned short* WC2h, unsigned short* WC2m,
                            unsigned short* WM1h, unsigned short* WM1m,
                            unsigned short* WM2h, unsigned short* WM2m){
  int gid = blockIdx.x*256 + threadIdx.x;
  const int S0 = 3*128*128;
  const int S1 = S0 + 3*128*128;
  const int S2 = S1 + 3*128*128;
  const int S3 = S2 + 128*128;
  const int S4 = S3 + 128*64;
  if(gid < S0)      splitW_one(bond_W,  WBh,  WBm,  gid,      128);
  else if(gid < S1) splitW_one(conv_W1, WC1h, WC1m, gid-S0,   128);
  else if(gid < S2) splitW_one(conv_W2, WC2h, WC2m, gid-S1,   128);
  else if(gid < S3) splitW_one(mlp_W1,  WM1h, WM1m, gid-S2,   128);
  else if(gid < S4) splitW_one(mlp_W2,  WM2h, WM2m, gid-S3,    64);
}

// ---------- edge prep: CSR-permuted edge_attr bf16 plane + edge mask (fused)
__global__ void k_edgeprep(const float* __restrict__ A, const int* __restrict__ eid,
                           const int* __restrict__ src, const int* __restrict__ dst,
                           const float* __restrict__ nm,
                           unsigned short* __restrict__ oh, float4* __restrict__ em4p){
  int tid = blockIdx.x*256 + threadIdx.x;
  if(tid >= EE*32) return;
  int j = tid >> 5, kq = tid & 31;
  int k = kq*4;
  int e = eid[j];
  float4 v = *(const float4*)&A[(size_t)e*H + k];
  ushort4 hh;
  hh.x = bf16rne(v.x); hh.y = bf16rne(v.y);
  hh.z = bf16rne(v.z); hh.w = bf16rne(v.w);
  *(ushort4*)&oh[(size_t)j*H + k] = hh;
  if(kq == 0){
    int s = src[e], d = dst[e];
    float4 m;
    m.x = nm[0*NN+s]*nm[0*NN+d];
    m.y = nm[1*NN+s]*nm[1*NN+d];
    m.z = nm[2*NN+s]*nm[2*NN+d];
    m.w = nm[3*NN+s]*nm[3*NN+d];
    em4p[j] = m;
  }
}

// ---------- 3-layer emb GEMM, single A pass, 4-deep W prefetch ring
__global__ __launch_bounds__(256) void k_egemm(
    const unsigned short* __restrict__ Ah,
    const unsigned short* __restrict__ WBh, const unsigned short* __restrict__ WBm,
    const float* __restrict__ bond_b, unsigned short* __restrict__ embB3){
  int t = threadIdx.x;
  int w = t >> 6, lane = t & 63;
  int m15 = lane & 15, kg = lane >> 4;
  int rowbase = blockIdx.x*128;

  short8 ahf[2][4];
  #pragma unroll
  for(int mf=0;mf<2;mf++){
    int arow = rowbase + w*32 + mf*16 + m15;
    #pragma unroll
    for(int ks=0;ks<4;ks++){
      size_t base = (size_t)arow*H + ks*32 + kg*4;
      ushort4 hlo = *(const ushort4*)&Ah[base];
      ushort4 hhi = *(const ushort4*)&Ah[base + 16];
      ahf[mf][ks] = (short8){(short)hlo.x,(short)hlo.y,(short)hlo.z,(short)hlo.w,
                             (short)hhi.x,(short)hhi.y,(short)hhi.z,(short)hhi.w};
    }
  }

  for(int layer=0; layer<3; layer++){
    const unsigned short* Wh = WBh + layer*16384;
    const unsigned short* Wm = WBm + layer*16384;
    const float* bias = bond_b + layer*H;
    unsigned short* Oh = embB3 + (size_t)layer*EE*H;

    const int SMAX = 31;
    auto ldW = [&](int s, short8* d){
      size_t widx = ((size_t)s*64 + lane)*8;
      d[0] = *(const short8*)&Wh[widx];
      d[1] = *(const short8*)&Wm[widx];
    };

    f32x4 acc[2][8];
    #pragma unroll
    for(int mf=0;mf<2;mf++)
      #pragma unroll
      for(int nf=0;nf<8;nf++) acc[mf][nf] = (f32x4){0.f,0.f,0.f,0.f};

    short8 wb[4][2];
    ldW(0, wb[0]); ldW(1, wb[1]); ldW(2, wb[2]); ldW(3, wb[3]);

    for(int ks=0;ks<4;ks++){
      #pragma unroll
      for(int nf=0;nf<8;nf++){
        int s = ks*8 + nf;
        const int slot = nf & 3;
        #pragma unroll
        for(int mf=0;mf<2;mf++){
          acc[mf][nf] = __builtin_amdgcn_mfma_f32_16x16x32_bf16(ahf[mf][ks], wb[slot][0], acc[mf][nf], 0,0,0);
          acc[mf][nf] = __builtin_amdgcn_mfma_f32_16x16x32_bf16(ahf[mf][ks], wb[slot][1], acc[mf][nf], 0,0,0);
        }
        int ns = s + 4; if(ns > SMAX) ns = SMAX;
        ldW(ns, wb[slot]);
      }
    }
    #pragma unroll
    for(int mf=0;mf<2;mf++){
      #pragma unroll
      for(int nf=0;nf<8;nf++){
        int gcol = nf*16 + m15;
        float bv = bias[gcol];
        #pragma unroll
        for(int r=0;r<4;r++){
          int grow = rowbase + w*32 + mf*16 + kg*4 + r;
          Oh[(size_t)grow*H + gcol] = bf16rne(acc[mf][nf][r] + bv);
        }
      }
    }
  }
}

// ---------- FUSED double GEMM, 16 rows/wave, wave-private u tile, 4-deep W ring
template<int NFO2, bool G2, int OMODE>
__global__ __launch_bounds__(256) void k_fuse2(
    const unsigned short* __restrict__ Ah, const unsigned short* __restrict__ Am,
    const unsigned short* __restrict__ W1h, const unsigned short* __restrict__ W1m,
    const float* __restrict__ b1,
    const unsigned short* __restrict__ W2h, const unsigned short* __restrict__ W2m,
    const float* __restrict__ b2,
    float* __restrict__ Cf,
    unsigned short* __restrict__ Oh, unsigned short* __restrict__ Om, int nrows){
  __shared__ unsigned int Ul[4*16*132];
  int t = threadIdx.x;
  int w = t >> 6, lane = t & 63;
  int m15 = lane & 15, kg = lane >> 4;
  int rowbase = blockIdx.x*64;
  unsigned int* Uw = &Ul[w*16*132];

  int r0 = rowbase + w*16 + m15;
  int arow = (r0 < nrows) ? r0 : (nrows-1);

  // ---- phase 1: u = gelu(A@W1 + b1)
  {
    const int SMAX = 31;
    auto ldW = [&](int s, short8* d){
      size_t widx = ((size_t)s*64 + lane)*8;
      d[0] = *(const short8*)&W1h[widx];
      d[1] = *(const short8*)&W1m[widx];
    };
    f32x4 acc[8];
    #pragma unroll
    for(int nf=0;nf<8;nf++) acc[nf] = (f32x4){0.f,0.f,0.f,0.f};
    short8 wb[4][2];
    ldW(0, wb[0]); ldW(1, wb[1]); ldW(2, wb[2]); ldW(3, wb[3]);
    for(int ks=0;ks<4;ks++){
      short8 ah, am;
      {
        size_t base = (size_t)arow*H + ks*32 + kg*4;
        ushort4 hlo = *(const ushort4*)&Ah[base];
        ushort4 hhi = *(const ushort4*)&Ah[base + 16];
        ushort4 mlo = *(const ushort4*)&Am[base];
        ushort4 mhi = *(const ushort4*)&Am[base + 16];
        ah = (short8){(short)hlo.x,(short)hlo.y,(short)hlo.z,(short)hlo.w,
                      (short)hhi.x,(short)hhi.y,(short)hhi.z,(short)hhi.w};
        am = (short8){(short)mlo.x,(short)mlo.y,(short)mlo.z,(short)mlo.w,
                      (short)mhi.x,(short)mhi.y,(short)mhi.z,(short)mhi.w};
      }
      #pragma unroll
      for(int nf=0;nf<8;nf++){
        int s = ks*8 + nf;
        const int slot = nf & 3;
        acc[nf] = __builtin_amdgcn_mfma_f32_16x16x32_bf16(ah, wb[slot][0], acc[nf], 0,0,0);
        acc[nf] = __builtin_amdgcn_mfma_f32_16x16x32_bf16(ah, wb[slot][1], acc[nf], 0,0,0);
        acc[nf] = __builtin_amdgcn_mfma_f32_16x16x32_bf16(am, wb[slot][0], acc[nf], 0,0,0);
        int ns = s + 4; if(ns > SMAX) ns = SMAX;
        ldW(ns, wb[slot]);
      }
    }
    #pragma unroll
    for(int nf=0;nf<8;nf++){
      float bv = b1[nf*16 + m15];
      #pragma unroll
      for(int r=0;r<4;r++){
        float v = gelu_f(acc[nf][r] + bv);
        unsigned short hh, mm2;
        split2(v, hh, mm2);
        int wrow = kg*4 + r;
        Uw[wrow*132 + nf*16 + m15] = (unsigned)hh | ((unsigned)mm2 << 16);
      }
    }
  }
  // no barrier: u tile is strictly wave-private

  // ---- phase 2: out = act2(u @ W2 + b2)
  {
    const int SMAX = 4*NFO2 - 1;
    auto ldW = [&](int s, short8* d){
      size_t widx = ((size_t)s*64 + lane)*8;
      d[0] = *(const short8*)&W2h[widx];
      d[1] = *(const short8*)&W2m[widx];
    };
    f32x4 acc[NFO2];
    #pragma unroll
    for(int nf=0;nf<NFO2;nf++) acc[nf] = (f32x4){0.f,0.f,0.f,0.f};
    short8 wb[4][2];
    ldW(0, wb[0]);
    ldW(1 <= SMAX ? 1 : SMAX, wb[1]);
    ldW(2 <= SMAX ? 2 : SMAX, wb[2]);
    ldW(3 <= SMAX ? 3 : SMAX, wb[3]);
    for(int ks=0;ks<4;ks++){
      short8 ah, am;
      {
        const unsigned int* base = &Uw[m15*132 + ks*32 + kg*4];
        uint4 q0 = *(const uint4*)base;
        uint4 q1 = *(const uint4*)(base + 16);
        unsigned h0 = (q0.x & 0xFFFFu) | (q0.y << 16);
        unsigned h1 = (q0.z & 0xFFFFu) | (q0.w << 16);
        unsigned h2 = (q1.x & 0xFFFFu) | (q1.y << 16);
        unsigned h3 = (q1.z & 0xFFFFu) | (q1.w << 16);
        unsigned M0 = (q0.x >> 16) | (q0.y & 0xFFFF0000u);
        unsigned M1 = (q0.z >> 16) | (q0.w & 0xFFFF0000u);
        unsigned M2 = (q1.x >> 16) | (q1.y & 0xFFFF0000u);
        unsigned M3 = (q1.z >> 16) | (q1.w & 0xFFFF0000u);
        union { uint4 u; short8 s; } cvh, cvm;
        cvh.u = (uint4){h0,h1,h2,h3};
        cvm.u = (uint4){M0,M1,M2,M3};
        ah = cvh.s; am = cvm.s;
      }
      #pragma unroll
      for(int nf=0;nf<NFO2;nf++){
        int s = ks*NFO2 + nf;
        const int slot = nf & 3;
        acc[nf] = __builtin_amdgcn_mfma_f32_16x16x32_bf16(ah, wb[slot][0], acc[nf], 0,0,0);
        acc[nf] = __builtin_amdgcn_mfma_f32_16x16x32_bf16(ah, wb[slot][1], acc[nf], 0,0,0);
        acc[nf] = __builtin_amdgcn_mfma_f32_16x16x32_bf16(am, wb[slot][0], acc[nf], 0,0,0);
        int ns = s + 4; if(ns > SMAX) ns = SMAX;
        ldW(ns, wb[slot]);
      }
    }
    #pragma unroll
    for(int nf=0;nf<NFO2;nf++){
      int gcol = nf*16 + m15;
      float bv = b2[gcol];
      #pragma unroll
      for(int r=0;r<4;r++){
        int grow = rowbase + w*16 + kg*4 + r;
        if(grow >= nrows) continue;
        float v = acc[nf][r] + bv;
        if(G2) v = gelu_f(v);
        size_t idx = (size_t)grow*(NFO2*16) + gcol;
        if(OMODE == 0) Cf[idx] = v;
        if(OMODE == 1){
          unsigned short hh, mm2;
          split2(v, hh, mm2);
          Oh[idx] = hh; Om[idx] = mm2;
        }
        if(OMODE == 2) Oh[idx] = bf16rne(v);
      }
    }
  }
}

// ---------- aggregation: CSR streams; bf16 emb; fp32 node-major h gather;
// 3-slot SHIFTING pipeline; degree-desc wave order; tanh-gelu
template<bool FIRST>
__global__ __launch_bounds__(256) void k_agg(const float* __restrict__ hin,
                       const unsigned short* __restrict__ embB, const float4* __restrict__ em4p,
                       const int* __restrict__ rs, const int* __restrict__ esrc,
                       const int* __restrict__ nord,
                       const float* __restrict__ epsp,
                       unsigned short* __restrict__ Th, unsigned short* __restrict__ Tm){
  int t = threadIdx.x;
  int w = t >> 6;
  int lane = t & 63;
  int half = lane >> 5;
  int l32 = lane & 31;
  int n = nord[blockIdx.x*4 + w];
  int d0 = l32*4;
  int rc0 = half*2, rc1 = rc0+1;
  float4 acc0 = {0.f,0.f,0.f,0.f}, acc1 = {0.f,0.f,0.f,0.f};
  int jb = rs[n], je = rs[n+1];

  float4 evs[3], h0s[3], h1s[3];
  float  m0s[3], m1s[3];

  auto ld = [&](int j, int slot){
    int s = esrc[j];
    ushort4 e4 = *(const ushort4*)&embB[(size_t)j*H + d0];
    evs[slot].x = bf2f(e4.x); evs[slot].y = bf2f(e4.y);
    evs[slot].z = bf2f(e4.z); evs[slot].w = bf2f(e4.w);
    float4 m = em4p[j];
    m0s[slot] = half ? m.z : m.x;
    m1s[slot] = half ? m.w : m.y;
    if(FIRST){
      h0s[slot] = *(const float4*)&hin[(size_t)s*H + d0];
      h1s[slot] = h0s[slot];
    } else {
      h0s[slot] = *(const float4*)&hin[((size_t)s*RCN + rc0)*H + d0];
      h1s[slot] = *(const float4*)&hin[((size_t)s*RCN + rc1)*H + d0];
    }
  };

  if(jb < je){
    ld(jb, 0);
    if(jb+1 < je) ld(jb+1, 1);
    if(jb+2 < je) ld(jb+2, 2);
    for(int j=jb; j<je; j++){
      float4 ev0 = evs[0], h00 = h0s[0], h10 = h1s[0];
      float  m00 = m0s[0], m10 = m1s[0];
      evs[0]=evs[1]; h0s[0]=h0s[1]; h1s[0]=h1s[1]; m0s[0]=m0s[1]; m1s[0]=m1s[1];
      evs[1]=evs[2]; h0s[1]=h0s[2]; h1s[1]=h1s[2]; m0s[1]=m0s[2]; m1s[1]=m1s[2];
      if(j+3 < je) ld(j+3, 2);
      if(FIRST){
        float gx = gelu_t(h00.x+ev0.x);
        float gy = gelu_t(h00.y+ev0.y);
        float gz = gelu_t(h00.z+ev0.z);
        float gw = gelu_t(h00.w+ev0.w);
        acc0.x += gx*m00; acc0.y += gy*m00; acc0.z += gz*m00; acc0.w += gw*m00;
        acc1.x += gx*m10; acc1.y += gy*m10; acc1.z += gz*m10; acc1.w += gw*m10;
      } else {
        acc0.x += gelu_t(h00.x+ev0.x)*m00;
        acc0.y += gelu_t(h00.y+ev0.y)*m00;
        acc0.z += gelu_t(h00.z+ev0.z)*m00;
        acc0.w += gelu_t(h00.w+ev0.w)*m00;
        acc1.x += gelu_t(h10.x+ev0.x)*m10;
        acc1.y += gelu_t(h10.y+ev0.y)*m10;
        acc1.z += gelu_t(h10.z+ev0.z)*m10;
        acc1.w += gelu_t(h10.w+ev0.w)*m10;
      }
    }
  }
  float e1 = 1.0f + epsp[0];
  #pragma unroll
  for(int p=0;p<2;p++){
    int rc = p ? rc1 : rc0;
    float4 ac = p ? acc1 : acc0;
    const float* hb = FIRST ? (hin + (size_t)n*H) : (hin + ((size_t)n*RCN + rc)*H);
    float4 hv = *(const float4*)&hb[d0];
    float4 o;
    o.x = e1*hv.x + ac.x; o.y = e1*hv.y + ac.y;
    o.z = e1*hv.z + ac.z; o.w = e1*hv.w + ac.w;
    int row = n*RCN + rc;               // node-major
    ushort4 hh, mm;
    split2(o.x, hh.x, mm.x);
    split2(o.y, hh.y, mm.y);
    split2(o.z, hh.z, mm.z);
    split2(o.w, hh.w, mm.w);
    size_t idx = (size_t)row*H + d0;
    *(ushort4*)&Th[idx] = hh;
    *(ushort4*)&Tm[idx] = mm;
  }
}

// ---------- deterministic masked segment mean (node-major y rows)
__global__ __launch_bounds__(64) void k_pool(const float* __restrict__ y, const float* __restrict__ nm,
                       const int* __restrict__ gs, float* __restrict__ out){
  int seg = blockIdx.x;
  int rc = seg / NG;
  int g  = seg - rc*NG;
  int c  = threadIdx.x;
  int nb = gs[g], ne = gs[g+1];
  float num = 0.f, den = 0.f;
  for(int n=nb; n<ne; n++){
    float w = nm[rc*NN + n];
    num += y[((size_t)n*RCN + rc)*OUTF + c] * w;
    den += w;
  }
  out[seg*OUTF + c] = num / fmaxf(den, 1e-12f);
}

extern "C" void kernel_launch(void* const* d_in, const int* in_sizes, int n_in,
                              void* d_out, int out_size, void* d_ws, size_t ws_size,
                              hipStream_t stream){
  const float* x         = (const float*)d_in[0];
  const float* edge_attr = (const float*)d_in[1];
  const float* node_mask = (const float*)d_in[2];
  const float* bond_W    = (const float*)d_in[3];
  const float* bond_b    = (const float*)d_in[4];
  const float* epsv      = (const float*)d_in[5];
  const float* conv_W1   = (const float*)d_in[6];
  const float* conv_b1   = (const float*)d_in[7];
  const float* conv_W2   = (const float*)d_in[8];
  const float* conv_b2   = (const float*)d_in[9];
  const float* mlp_W1    = (const float*)d_in[10];
  const float* mlp_b1    = (const float*)d_in[11];
  const float* mlp_W2    = (const float*)d_in[12];
  const float* mlp_b2    = (const float*)d_in[13];
  const int*   eidx      = (const int*)d_in[14];
  const int*   batch     = (const int*)d_in[15];
  const int* srcp = eidx;
  const int* dstp = eidx + EE;

  char* p = (char*)d_ws;
  auto alloc = [&](size_t bytes)->char*{
    char* r = p; p += (bytes + 255) & ~size_t(255); return r;
  };
  float*  h    = (float*) alloc((size_t)RCN*NN*H*4);      // 20.5 MB fp32 node-major
  unsigned short* embB3 = (unsigned short*)alloc((size_t)3*EE*H*2); // 123 MB bf16 (3 layers)
  float4* em4p = (float4*)alloc((size_t)EE*16);           //  2.6 MB
  float*  y    = (float*) alloc((size_t)RCN*NN*OUTF*4);   // 10.2 MB
  int*    cnt  = (int*)   alloc((size_t)NN*4);
  int*    rs   = (int*)   alloc((size_t)(NN+1)*4);
  int*    cur  = (int*)   alloc((size_t)NN*4);
  int*    eid  = (int*)   alloc((size_t)EE*4);
  int*    esrc = (int*)   alloc((size_t)EE*4);
  int*    gs   = (int*)   alloc((size_t)(NG+1)*4);
  int*    dcnt = (int*)   alloc((size_t)256*4);
  int*    dcur = (int*)   alloc((size_t)256*4);
  int*    nord = (int*)   alloc((size_t)NN*4);
  // weight planes (bf16x2, frag-linear)
  unsigned short* WBh  = (unsigned short*)alloc((size_t)3*16384*2);
  unsigned short* WBm  = (unsigned short*)alloc((size_t)3*16384*2);
  unsigned short* WC1h = (unsigned short*)alloc((size_t)3*16384*2);
  unsigned short* WC1m = (unsigned short*)alloc((size_t)3*16384*2);
  unsigned short* WC2h = (unsigned short*)alloc((size_t)3*16384*2);
  unsigned short* WC2m = (unsigned short*)alloc((size_t)3*16384*2);
  unsigned short* WM1h = (unsigned short*)alloc((size_t)16384*2);
  unsigned short* WM1m = (unsigned short*)alloc((size_t)16384*2);
  unsigned short* WM2h = (unsigned short*)alloc((size_t)8192*2);
  unsigned short* WM2m = (unsigned short*)alloc((size_t)8192*2);
  // edge_attr single bf16 plane (CSR-permuted, row-major): 41 MB
  unsigned short* EAh  = (unsigned short*)alloc((size_t)EE*H*2);
  // node activation planes (row-major bf16x2)
  const size_t NPB = (size_t)RCN*NN*H*2;
  unsigned short* TBh = (unsigned short*)alloc(NPB);
  unsigned short* TBm = (unsigned short*)alloc(NPB);
  if((size_t)(p - (char*)d_ws) > ws_size) return;   // total ~222 MB

  hipMemsetAsync(cnt, 0, (size_t)NN*4, stream);
  hipMemsetAsync(dcnt, 0, (size_t)256*4, stream);

  k_hist     <<<(EE+255)/256, 256, 0, stream>>>(dstp, cnt);
  k_scan     <<<1, 1024, 0, stream>>>(cnt, rs, cur, dcnt);
  k_fill     <<<(EE+255)/256, 256, 0, stream>>>(dstp, cur, eid);
  k_sortcsr  <<<(NN*64+255)/256, 256, 0, stream>>>(rs, eid, srcp, esrc);
  k_misc     <<<2, 256, 0, stream>>>(dcnt, dcur, batch, gs);
  k_dfill    <<<(NN+255)/256, 256, 0, stream>>>(rs, dcur, nord);
  k_edgeprep <<<(EE*32+255)/256, 256, 0, stream>>>(edge_attr, eid, srcp, dstp,
                                                   node_mask, EAh, em4p);
  k_splitWall<<<(172032+255)/256, 256, 0, stream>>>(bond_W, conv_W1, conv_W2, mlp_W1, mlp_W2,
                                                    WBh, WBm, WC1h, WC1m, WC2h, WC2m,
                                                    WM1h, WM1m, WM2h, WM2m);
  // all 3 emb layers in one launch, single A pass
  k_egemm    <<<EE/128, 256, 0, stream>>>(EAh, WBh, WBm, bond_b, embB3);

  const int NROWS = RCN*NN;
  const int GB_F = (NROWS+63)/64;      // 625 blocks for fuse2
  for(int l=0; l<3; l++){
    size_t wo = (size_t)l*16384;
    const unsigned short* embB = embB3 + (size_t)l*EE*H;
    if(l == 0)
      k_agg<true ><<<NN/4, 256, 0, stream>>>(x, embB, em4p, rs, esrc, nord,
                                             epsv + l, TBh, TBm);
    else
      k_agg<false><<<NN/4, 256, 0, stream>>>(h, embB, em4p, rs, esrc, nord,
                                             epsv + l, TBh, TBm);
    // fused conv: h = gelu(gelu(t@W1+b1)@W2+b2)
    if(l < 2)
      k_fuse2<8,true,0><<<GB_F, 256, 0, stream>>>(
          TBh, TBm, WC1h+wo, WC1m+wo, conv_b1 + l*H,
          WC2h+wo, WC2m+wo, conv_b2 + l*H, h, nullptr, nullptr, NROWS);
    else
      k_fuse2<8,true,1><<<GB_F, 256, 0, stream>>>(
          TBh, TBm, WC1h+wo, WC1m+wo, conv_b1 + l*H,
          WC2h+wo, WC2m+wo, conv_b2 + l*H, nullptr, TBh, TBm, NROWS);
  }
  // fused MLP: y = gelu(hp@W1+b1)@W2+b2
  k_fuse2<4,false,0><<<GB_F, 256, 0, stream>>>(
      TBh, TBm, WM1h, WM1m, mlp_b1, WM2h, WM2m, mlp_b2,
      y, nullptr, nullptr, NROWS);
  k_pool<<<DSEG, 64, 0, stream>>>(y, node_mask, gs, (float*)d_out);
}